// Round 6
// baseline (1800.884 us; speedup 1.0000x reference)
//
#include <hip/hip_runtime.h>
#include <hip/hip_fp16.h>
#include <stdint.h>

#define B_TOTAL 1024
#define T_TOTAL 1024
#define LOG2E 1.44269504088896f

typedef _Float16 f16x2 __attribute__((ext_vector_type(2)));

__device__ __forceinline__ float dot2w(uint32_t xw, uint32_t ww, float acc) {
#if __has_builtin(__builtin_amdgcn_fdot2)
    return __builtin_amdgcn_fdot2(__builtin_bit_cast(f16x2, xw),
                                  __builtin_bit_cast(f16x2, ww), acc, false);
#else
    f16x2 xv = __builtin_bit_cast(f16x2, xw);
    f16x2 wv = __builtin_bit_cast(f16x2, ww);
    return acc + (float)xv.x * (float)wv.x + (float)xv.y * (float)wv.y;
#endif
}

__device__ __forceinline__ uint32_t packf2(float a, float b) {
    f16x2 t;
    t.x = (_Float16)a;
    t.y = (_Float16)b;
    return __builtin_bit_cast(uint32_t, t);
}

__device__ __forceinline__ float sigm_(float z) {
    float e = __builtin_amdgcn_exp2f(-LOG2E * z);
    return __builtin_amdgcn_rcpf(1.0f + e);
}
__device__ __forceinline__ float tanh_(float z) {
    float e = __builtin_amdgcn_exp2f((2.0f * LOG2E) * z);
    float r = __builtin_amdgcn_rcpf(1.0f + e);
    return __builtin_fmaf(-2.0f, r, 1.0f);
}

__device__ __forceinline__ void wavebar() {
#if __has_builtin(__builtin_amdgcn_wave_barrier)
    __builtin_amdgcn_wave_barrier();
#endif
}

// ====================== projection pass (round 6) ======================
// Computes Gx[i*B+b][4H] f16 = in[t(i)][b][:] @ W_ih^T for ONE T-segment,
// both directions (blockIdx.y = dir). Row i is the i-th scan step of the
// segment: fwd t = t0+i, bwd t = T-1-t0-i (so the scan reads rows 0..seglen
// in step order for both dirs). Output column o = j*4+q (unit-major) so a
// scan lane reads its 4 gates as one b64. NO bias (scan adds it).
// Massively parallel: saturates the chip the serial scan leaves idle.
template <int DIN, int H, int NDIR, bool L1X>
__global__ void __launch_bounds__(256) proj_kernel(
    const float* __restrict__ x,        // L1X: [B][T][8] f32
    const __half* __restrict__ inbuf,   // else: [T][B][DIN] f16
    const float* __restrict__ w0,       // W_ih fwd [4H][DIN] f32
    const float* __restrict__ w1,       // W_ih bwd
    __half* __restrict__ g0,            // Gx fwd [seglen*B][4H] f16
    __half* __restrict__ g1,            // Gx bwd
    int t0, int seglen)                 // segment = steps [t0, t0+seglen)
{
    constexpr int NDW = DIN / 2;       // input dwords (f16 pairs)
    constexpr int O4H = 4 * H;         // outputs per dir
    constexpr int ODW = O4H / 2;       // out dwords per row
    constexpr int RPB = 16;            // rows per tile
    constexpr int TPR = 16;            // threads per row
    constexpr int OPT = (O4H + TPR - 1) / TPR;
    constexpr int TILES = 8;           // tiles per block

    __shared__ uint32_t wt[NDW][O4H];
    __shared__ uint32_t xin[RPB * NDW];
    __shared__ uint32_t osm[RPB][ODW];

    const int tid  = threadIdx.x;
    const int dirz = (NDIR == 2) ? (int)blockIdx.y : 0;
    const float* w = dirz ? w1 : w0;
    __half* gout   = dirz ? g1 : g0;
    (void)seglen;

    // stage W^T once per block: wt[d][o], o = j*4 + q
    for (int idx = tid; idx < NDW * O4H; idx += 256) {
        const int d  = idx / O4H;
        const int o  = idx - d * O4H;
        const int jj = o >> 2;
        const int qq = o & 3;
        wt[d][o] = packf2(w[(qq * H + jj) * DIN + 2 * d],
                          w[(qq * H + jj) * DIN + 2 * d + 1]);
    }

    const int rr = tid >> 4;   // row within tile
    const int li = tid & 15;   // thread within row

    for (int tile = 0; tile < TILES; ++tile) {
        const int r0 = ((int)blockIdx.x * TILES + tile) * RPB;
        __syncthreads();   // wt ready / prev tile's flush done

        // ---- load 16 input rows ----
        for (int idx = tid; idx < RPB * NDW; idx += 256) {
            const int r  = r0 + idx / NDW;
            const int d  = idx % NDW;
            const int i  = r >> 10;               // B_TOTAL = 1024
            const int bb = r & (B_TOTAL - 1);
            const int t  = dirz ? (T_TOTAL - 1 - t0 - i) : (t0 + i);
            uint32_t v;
            if constexpr (L1X) {
                float2 u = {0.f, 0.f};
                if (d < 4)
                    u = ((const float2*)(x + ((size_t)bb * T_TOTAL + t) * 8))[d];
                else if (t > 0)
                    u = ((const float2*)(x + ((size_t)bb * T_TOTAL + (t - 1)) * 8))[d - 4];
                v = packf2(u.x, u.y);
            } else {
                v = ((const uint32_t*)inbuf)[((size_t)t * B_TOTAL + bb) * NDW + d];
            }
            xin[idx] = v;
        }
        __syncthreads();

        // ---- dots: xin broadcast x wt (conflict-free patterns) ----
        float acc[OPT];
#pragma unroll
        for (int oi = 0; oi < OPT; ++oi) acc[oi] = 0.f;
#pragma unroll
        for (int d = 0; d < NDW; ++d) {
            const uint32_t xv = xin[rr * NDW + d];
#pragma unroll
            for (int oi = 0; oi < OPT; ++oi) {
                const int o = li + oi * TPR;
                if (O4H % TPR == 0 || o < O4H)
                    acc[oi] = dot2w(xv, wt[d][o], acc[oi]);
            }
        }
        {
            __half* oh = (__half*)&osm[rr][0];
#pragma unroll
            for (int oi = 0; oi < OPT; ++oi) {
                const int o = li + oi * TPR;
                if (O4H % TPR == 0 || o < O4H) oh[o] = __float2half(acc[oi]);
            }
        }
        __syncthreads();   // osm ready

        // ---- coalesced flush ----
        {
            uint32_t* dst = (uint32_t*)gout;
            for (int idx = tid; idx < RPB * ODW; idx += 256) {
                const int r  = idx / ODW;
                const int od = idx - r * ODW;
                dst[(size_t)(r0 + r) * ODW + od] = osm[r][od];
            }
        }
    }
}

// ======================= lean scan pass (round 6) =======================
// Per step: ONE b64 global Gx load (8-deep register ring, clamped tail),
// 4 cvt+bias, NH*4 h-dots, activations, h LDS broadcast (uint4 reads).
// (h,c) state persists across segment launches in sth/stc.
// W_hh pinned in VGPRs via opaque asm (r0-r3 remat lesson).
template <int H, bool STORE_ALL>
__global__ void __launch_bounds__(64)
__attribute__((amdgpu_waves_per_eu(1, 1))) lstm_scan2(
    const __half* __restrict__ gxf, const __half* __restrict__ gxb,
    const float* __restrict__ whhf, const float* __restrict__ bihf,
    const float* __restrict__ bhhf,
    const float* __restrict__ whhb, const float* __restrict__ bihb,
    const float* __restrict__ bhhb,
    __half* __restrict__ outbuf,    // STORE_ALL: [T][B][2H] f16
    float* __restrict__ lasth,      // !STORE_ALL: [B][H] f32
    float* __restrict__ sth, float* __restrict__ stc,  // [2][B][H] f32 state
    int t0, int seglen)
{
    constexpr int GPW   = 64 / H;
    constexpr int NH    = H / 2;
    constexpr int HS_DW = (H == 20) ? 12 : 8;
    constexpr int PF    = 8;

    const int dir  = blockIdx.y;
    const int lane = threadIdx.x;
    const int g    = lane / H;
    const int j    = lane - g * H;
    const int b    = blockIdx.x * GPW + g;
    const bool valid = (g < GPW) && (b < B_TOTAL);
    const int bs   = valid ? b : (B_TOTAL - 1);

    const __half* gx  = dir ? gxb : gxf;
    const float* w_hh = dir ? whhb : whhf;
    const float* b_i  = dir ? bihb : bihf;
    const float* b_h  = dir ? bhhb : bhhf;

    __shared__ uint32_t hsm[GPW + 1][HS_DW];

    uint32_t whh2[4][NH];
    float bias[4];
#pragma unroll
    for (int q = 0; q < 4; ++q) {
        const int r = q * H + j;
#pragma unroll
        for (int k = 0; k < NH; ++k)
            whh2[q][k] = packf2(w_hh[r * H + 2 * k], w_hh[r * H + 2 * k + 1]);
        bias[q] = b_i[r] + b_h[r];
    }
#pragma unroll
    for (int q = 0; q < 4; ++q) {
#pragma unroll
        for (int k = 0; k < NH; ++k) asm volatile("" : "+v"(whh2[q][k]));
        asm volatile("" : "+v"(bias[q]));
    }

    // ---- state (zeros at t0==0, else persisted) ----
    float c_st, h0;
    if (t0 == 0) {
        c_st = 0.f;
        h0   = 0.f;
    } else {
        h0   = sth[((size_t)dir * B_TOTAL + bs) * H + j];
        c_st = stc[((size_t)dir * B_TOTAL + bs) * H + j];
    }
    ((__half*)&hsm[g][0])[j] = __float2half(h0);
    wavebar();

    uint32_t hd[NH];
    auto readhd = [&]() {
        const uint32_t* hp = &hsm[g][0];
        if constexpr (NH == 10) {
            uint4 v0 = *(const uint4*)hp;
            uint4 v1 = *(const uint4*)(hp + 4);
            uint2 v2 = *(const uint2*)(hp + 8);
            hd[0] = v0.x; hd[1] = v0.y; hd[2] = v0.z; hd[3] = v0.w;
            hd[4] = v1.x; hd[5] = v1.y; hd[6] = v1.z; hd[7] = v1.w;
            hd[8] = v2.x; hd[9] = v2.y;
        } else {
            uint4 v0 = *(const uint4*)hp;
            hd[0] = v0.x; hd[1] = v0.y; hd[2] = v0.z; hd[3] = v0.w;
            hd[4] = hp[4];
        }
    };
    readhd();

    // ---- Gx prefetch ring (rows are seg-local step indices) ----
    const char*  gb   = (const char*)gx + ((size_t)bs * (4 * H) + (size_t)j * 4) * 2;
    const size_t ISTR = (size_t)B_TOTAL * (4 * H) * 2;

    uint2 pf[PF];
#pragma unroll
    for (int i2 = 0; i2 < PF; ++i2) {
        const int ip = (i2 < seglen) ? i2 : (seglen - 1);
        pf[i2] = *(const uint2*)(gb + (size_t)ip * ISTR);
    }

    __half* op = nullptr;
    ptrdiff_t opstep = 0;
    if constexpr (STORE_ALL) {
        const int tstart = dir ? (T_TOTAL - 1 - t0) : t0;
        op = outbuf + (size_t)tstart * (B_TOTAL * 2 * H) + (size_t)bs * (2 * H) + dir * H + j;
        opstep = (dir ? -1 : 1) * (ptrdiff_t)(B_TOTAL * 2 * H);
    }

    float hlast = h0;

#define STEP(I)                                                               \
    {                                                                         \
        const uint2 gv = pf[I];                                               \
        int ip = sb + (I) + PF;                                               \
        ip = (ip < seglen) ? ip : (seglen - 1);                               \
        pf[I] = *(const uint2*)(gb + (size_t)ip * ISTR);                      \
        const f16x2 p01 = __builtin_bit_cast(f16x2, gv.x);                    \
        const f16x2 p23 = __builtin_bit_cast(f16x2, gv.y);                    \
        float a0 = (float)p01.x + bias[0];                                    \
        float a1 = (float)p01.y + bias[1];                                    \
        float a2 = (float)p23.x + bias[2];                                    \
        float a3 = (float)p23.y + bias[3];                                    \
        _Pragma("unroll")                                                     \
        for (int k = 0; k < NH; ++k) {                                        \
            a0 = dot2w(hd[k], whh2[0][k], a0);                                \
            a1 = dot2w(hd[k], whh2[1][k], a1);                                \
            a2 = dot2w(hd[k], whh2[2][k], a2);                                \
            a3 = dot2w(hd[k], whh2[3][k], a3);                                \
        }                                                                     \
        const float iv = sigm_(a0);                                           \
        const float fv = sigm_(a1);                                           \
        const float gv2 = tanh_(a2);                                          \
        const float ov = sigm_(a3);                                           \
        c_st = __builtin_fmaf(fv, c_st, iv * gv2);                            \
        const float h = ov * tanh_(c_st);                                     \
        ((__half*)&hsm[g][0])[j] = __float2half(h);                           \
        wavebar();                                                            \
        readhd();                                                             \
        hlast = h;                                                            \
        if constexpr (STORE_ALL) {                                            \
            if (valid) *op = __float2half(h);                                 \
            op += opstep;                                                     \
        }                                                                     \
    }

    for (int sb = 0; sb < seglen; sb += PF) {
        STEP(0) STEP(1) STEP(2) STEP(3) STEP(4) STEP(5) STEP(6) STEP(7)
    }
#undef STEP

    if (valid) {
        sth[((size_t)dir * B_TOTAL + b) * H + j] = hlast;
        stc[((size_t)dir * B_TOTAL + b) * H + j] = c_st;
        if constexpr (!STORE_ALL) lasth[b * H + j] = hlast;
    }
}

// L4 backward needed only at t=T-1 (single step from zero state) + FC + sigmoid.
__global__ void final_kernel(const __half* __restrict__ l3out,  // [T][B][20] f16
                             const float* __restrict__ hf4,     // [B][10]
                             const float* __restrict__ w_ih,    // w4b_ih [40][20]
                             const float* __restrict__ b_ih,
                             const float* __restrict__ b_hh,
                             const float* __restrict__ fc_w,    // [20]
                             const float* __restrict__ fc_b,
                             float* __restrict__ out)           // [B]
{
    const int b = blockIdx.x * blockDim.x + threadIdx.x;
    if (b >= B_TOTAL) return;

    float in4[20];
    const __half* p = l3out + (size_t)(T_TOTAL - 1) * (B_TOTAL * 20) + (size_t)b * 20;
#pragma unroll
    for (int i = 0; i < 20; ++i) in4[i] = __half2float(p[i]);

    float z = fc_b[0];
#pragma unroll
    for (int k = 0; k < 10; ++k) z += fc_w[k] * hf4[b * 10 + k];

#pragma unroll
    for (int k = 0; k < 10; ++k) {
        float gi = b_ih[k]      + b_hh[k];
        float gg = b_ih[20 + k] + b_hh[20 + k];
        float go = b_ih[30 + k] + b_hh[30 + k];
#pragma unroll
        for (int i = 0; i < 20; ++i) {
            const float xi = in4[i];
            gi += w_ih[k * 20 + i]        * xi;
            gg += w_ih[(20 + k) * 20 + i] * xi;
            go += w_ih[(30 + k) * 20 + i] * xi;
        }
        const float cc = sigm_(gi) * tanh_(gg);
        const float hb = sigm_(go) * tanh_(cc);
        z += fc_w[10 + k] * hb;
    }
    out[b] = sigm_(z);
}

extern "C" void kernel_launch(void* const* d_in, const int* in_sizes, int n_in,
                              void* d_out, int out_size, void* d_ws, size_t ws_size,
                              hipStream_t stream) {
    const float* x = (const float*)d_in[0];
    auto W = [&](int li, int dr, int k) -> const float* {
        return (const float*)d_in[1 + (li - 1) * 8 + dr * 4 + k];
    };
    const float* fc_w = (const float*)d_in[33];
    const float* fc_b = (const float*)d_in[34];
    float* out = (float*)d_out;

    // ---- workspace layout ----
    // hA  [T][B][40] f16 (80MB): L1 out, L2 in/out IN-PLACE (same width;
    //     proj(seg s) consumes every row scan(seg s) writes -> safe).
    // hB  [T][B][20] f16 (40MB): L3 out.
    // sth/stc [2][B][20] f32: scan state across segment launches.
    // hf4 [B][10] f32.
    // gx  chunk: 2 dirs x SEG*B*(4H<=80) f16 -> SEG*320KB.
    const size_t HA_B = (size_t)T_TOTAL * B_TOTAL * 40 * 2;
    const size_t HB_B = (size_t)T_TOTAL * B_TOTAL * 20 * 2;
    const size_t ST_B = 2ull * B_TOTAL * 20 * 4;
    const size_t F4_B = (size_t)B_TOTAL * 10 * 4;

    char* p = (char*)d_ws;
    __half* hA = (__half*)p;  p += HA_B;
    __half* hB = (__half*)p;  p += HB_B;
    float* sth = (float*)p;   p += ST_B;
    float* stc = (float*)p;   p += ST_B;
    float* hf4 = (float*)p;   p += F4_B;
    __half* gx = (__half*)p;

    const size_t base = HA_B + HB_B + 2 * ST_B + F4_B;
    // largest segment whose Gx chunk fits (SEG=64 needs 140MB total; the r4
    // layout (160.8MB) ran on this ws, so 64 always fits).
    int SEG = 64;
    if      (ws_size >= base + 1024ull * 327680) SEG = 1024;
    else if (ws_size >= base +  512ull * 327680) SEG = 512;
    else if (ws_size >= base +  256ull * 327680) SEG = 256;
    else if (ws_size >= base +  128ull * 327680) SEG = 128;
    const int nseg = T_TOTAL / SEG;

    // Gx bwd-dir base offset (dense per-layer width 4H)
    auto g1of = [&](int H) { return gx + (size_t)SEG * 1024 * 4 * H; };

    // ---- L1: DIN=16 (x + lag), H=20 -> hA ----
    for (int s = 0; s < nseg; ++s) {
        proj_kernel<16, 20, 2, true><<<dim3(SEG * 8, 2), 256, 0, stream>>>(
            x, nullptr, W(1,0,0), W(1,1,0), gx, g1of(20), s * SEG, SEG);
        lstm_scan2<20, true><<<dim3(342, 2), 64, 0, stream>>>(
            gx, g1of(20), W(1,0,1), W(1,0,2), W(1,0,3),
                          W(1,1,1), W(1,1,2), W(1,1,3),
            hA, nullptr, sth, stc, s * SEG, SEG);
    }
    // ---- L2: DIN=40, H=20, hA -> hA (in-place) ----
    for (int s = 0; s < nseg; ++s) {
        proj_kernel<40, 20, 2, false><<<dim3(SEG * 8, 2), 256, 0, stream>>>(
            nullptr, hA, W(2,0,0), W(2,1,0), gx, g1of(20), s * SEG, SEG);
        lstm_scan2<20, true><<<dim3(342, 2), 64, 0, stream>>>(
            gx, g1of(20), W(2,0,1), W(2,0,2), W(2,0,3),
                          W(2,1,1), W(2,1,2), W(2,1,3),
            hA, nullptr, sth, stc, s * SEG, SEG);
    }
    // ---- L3: DIN=40, H=10, hA -> hB ----
    for (int s = 0; s < nseg; ++s) {
        proj_kernel<40, 10, 2, false><<<dim3(SEG * 8, 2), 256, 0, stream>>>(
            nullptr, hA, W(3,0,0), W(3,1,0), gx, g1of(10), s * SEG, SEG);
        lstm_scan2<10, true><<<dim3(171, 2), 64, 0, stream>>>(
            gx, g1of(10), W(3,0,1), W(3,0,2), W(3,0,3),
                          W(3,1,1), W(3,1,2), W(3,1,3),
            hB, nullptr, sth, stc, s * SEG, SEG);
    }
    // ---- L4 forward only: DIN=20, H=10, hB -> hf4 ----
    for (int s = 0; s < nseg; ++s) {
        proj_kernel<20, 10, 1, false><<<dim3(SEG * 8, 1), 256, 0, stream>>>(
            nullptr, hB, W(4,0,0), W(4,0,0), gx, gx, s * SEG, SEG);
        lstm_scan2<10, false><<<dim3(171, 1), 64, 0, stream>>>(
            gx, gx, W(4,0,1), W(4,0,2), W(4,0,3),
                    W(4,0,1), W(4,0,2), W(4,0,3),
            nullptr, hf4, sth, stc, s * SEG, SEG);
    }

    final_kernel<<<dim3(4), 256, 0, stream>>>(
        hB, hf4, W(4,1,0), W(4,1,2), W(4,1,3), fc_w, fc_b, out);
}